// Round 1
// baseline (868.901 us; speedup 1.0000x reference)
//
#include <hip/hip_runtime.h>

// ---------------------------------------------------------------------------
// GraphSAGE 2-layer (mean aggr) + linear classifier, fp32, N=100K, D=64, E=16N
// Strategy: build CSR (in-edges per dst) once, then gather-aggregate with one
// wave per node / one feature per lane; dense 64x64 layers via LDS-staged
// weights + shfl-broadcast FMA (no fp32 MFMA on CDNA4).
// ---------------------------------------------------------------------------

#define SCAN_BS 1024

__global__ void zero_i32_kernel(int* __restrict__ p, int n) {
  int i = blockIdx.x * blockDim.x + threadIdx.x;
  if (i < n) p[i] = 0;
}

__global__ void hist_kernel(const int* __restrict__ dst, int* __restrict__ deg, int ne) {
  int e = blockIdx.x * blockDim.x + threadIdx.x;
  if (e < ne) atomicAdd(&deg[dst[e]], 1);
}

// inclusive block scan for 1024 threads (16 waves of 64)
__device__ __forceinline__ int block_scan_inclusive_1024(int v, int* wsums) {
  int lane = threadIdx.x & 63;
  int wid = threadIdx.x >> 6;
  int s = v;
#pragma unroll
  for (int off = 1; off < 64; off <<= 1) {
    int t = __shfl_up(s, off);
    if (lane >= off) s += t;
  }
  if (lane == 63) wsums[wid] = s;
  __syncthreads();
  if (wid == 0) {
    int ws = (lane < 16) ? wsums[lane] : 0;
#pragma unroll
    for (int off = 1; off < 16; off <<= 1) {
      int t = __shfl_up(ws, off);
      if (lane >= off) ws += t;
    }
    if (lane < 16) wsums[lane] = ws;
  }
  __syncthreads();
  if (wid > 0) s += wsums[wid - 1];
  return s;
}

// per-block exclusive scan; block totals to bsums
__global__ void __launch_bounds__(SCAN_BS) scan_a_kernel(const int* __restrict__ deg,
                                                         int* __restrict__ local_excl,
                                                         int* __restrict__ bsums, int n) {
  __shared__ int wsums[16];
  int i = blockIdx.x * SCAN_BS + threadIdx.x;
  int v = (i < n) ? deg[i] : 0;
  int inc = block_scan_inclusive_1024(v, wsums);
  if (i < n) local_excl[i] = inc - v;
  if (threadIdx.x == SCAN_BS - 1) bsums[blockIdx.x] = inc;
}

// scan block totals (nb <= 1024); boffs[nb] = grand total
__global__ void __launch_bounds__(SCAN_BS) scan_b_kernel(const int* __restrict__ bsums,
                                                         int* __restrict__ boffs, int nb) {
  __shared__ int wsums[16];
  int v = (threadIdx.x < nb) ? bsums[threadIdx.x] : 0;
  int inc = block_scan_inclusive_1024(v, wsums);
  if ((int)threadIdx.x < nb) boffs[threadIdx.x] = inc - v;
  if ((int)threadIdx.x == nb - 1) boffs[nb] = inc;
}

// add block offsets; produce row_ptr (n+1) and cursor copy
__global__ void scan_c_kernel(int* __restrict__ row_ptr, int* __restrict__ cursor,
                              const int* __restrict__ boffs, int n, int nb) {
  int i = blockIdx.x * blockDim.x + threadIdx.x;
  if (i < n) {
    int v = row_ptr[i] + boffs[i >> 10];
    row_ptr[i] = v;
    cursor[i] = v;
  }
  if (i == n) row_ptr[n] = boffs[nb];
}

__global__ void scatter_kernel(const int* __restrict__ src, const int* __restrict__ dst,
                               int* __restrict__ cursor, int* __restrict__ col, int ne) {
  int e = blockIdx.x * blockDim.x + threadIdx.x;
  if (e < ne) {
    int d = dst[e];
    int pos = atomicAdd(&cursor[d], 1);
    col[pos] = src[e];
  }
}

// one wave per node, one feature per lane; mean of gathered rows
__global__ void __launch_bounds__(256) aggregate_kernel(const float* __restrict__ xin,
                                                        const int* __restrict__ row_ptr,
                                                        const int* __restrict__ col,
                                                        float* __restrict__ outp, int n) {
  int gwave = (blockIdx.x * 256 + threadIdx.x) >> 6;
  int lane = threadIdx.x & 63;
  if (gwave >= n) return;
  int start = row_ptr[gwave];
  int end = row_ptr[gwave + 1];
  float acc = 0.0f;
  for (int e = start; e < end; ++e) {
    int s = col[e];  // wave-uniform broadcast load
    acc += xin[(size_t)s * 64 + lane];
  }
  int d = end - start;
  float inv = 1.0f / (float)((d > 0) ? d : 1);
  outp[(size_t)gwave * 64 + lane] = acc * inv;
}

// out = relu(agg @ Wl + b + xin @ Wr); one wave per node, feature j = lane
__global__ void __launch_bounds__(256) lin_relu_kernel(const float* __restrict__ agg,
                                                       const float* __restrict__ xin,
                                                       const float* __restrict__ Wl,
                                                       const float* __restrict__ bias,
                                                       const float* __restrict__ Wr,
                                                       float* __restrict__ outp, int n) {
  __shared__ float sWl[4096];
  __shared__ float sWr[4096];
  __shared__ float sb[64];
  for (int i = threadIdx.x; i < 1024; i += 256) {
    ((float4*)sWl)[i] = ((const float4*)Wl)[i];
    ((float4*)sWr)[i] = ((const float4*)Wr)[i];
  }
  if (threadIdx.x < 64) sb[threadIdx.x] = bias[threadIdx.x];
  __syncthreads();
  int lane = threadIdx.x & 63;
  int gwave = (blockIdx.x * 256 + threadIdx.x) >> 6;
  int nwaves = (gridDim.x * 256) >> 6;
  for (int node = gwave; node < n; node += nwaves) {
    float a = agg[(size_t)node * 64 + lane];
    float xv = xin[(size_t)node * 64 + lane];
    float acc = sb[lane];
#pragma unroll
    for (int k = 0; k < 64; ++k) {
      acc = fmaf(__shfl(a, k), sWl[k * 64 + lane], acc);
      acc = fmaf(__shfl(xv, k), sWr[k * 64 + lane], acc);
    }
    outp[(size_t)node * 64 + lane] = fmaxf(acc, 0.0f);
  }
}

// h2 = agg @ Wl + b + hin @ Wr (no relu); out = h2 @ Wc + bc  -> [n, 2]
__global__ void __launch_bounds__(256) lin2_cls_kernel(const float* __restrict__ agg,
                                                       const float* __restrict__ hin,
                                                       const float* __restrict__ Wl,
                                                       const float* __restrict__ bias,
                                                       const float* __restrict__ Wr,
                                                       const float* __restrict__ Wc,
                                                       const float* __restrict__ bc,
                                                       float* __restrict__ outp, int n) {
  __shared__ float sWl[4096];
  __shared__ float sWr[4096];
  __shared__ float sb[64];
  __shared__ float sWc[128];
  __shared__ float sbc[2];
  for (int i = threadIdx.x; i < 1024; i += 256) {
    ((float4*)sWl)[i] = ((const float4*)Wl)[i];
    ((float4*)sWr)[i] = ((const float4*)Wr)[i];
  }
  if (threadIdx.x < 64) sb[threadIdx.x] = bias[threadIdx.x];
  if (threadIdx.x < 128) sWc[threadIdx.x] = Wc[threadIdx.x];
  if (threadIdx.x < 2) sbc[threadIdx.x] = bc[threadIdx.x];
  __syncthreads();
  int lane = threadIdx.x & 63;
  int gwave = (blockIdx.x * 256 + threadIdx.x) >> 6;
  int nwaves = (gridDim.x * 256) >> 6;
  for (int node = gwave; node < n; node += nwaves) {
    float a = agg[(size_t)node * 64 + lane];
    float xv = hin[(size_t)node * 64 + lane];
    float acc = sb[lane];
#pragma unroll
    for (int k = 0; k < 64; ++k) {
      acc = fmaf(__shfl(a, k), sWl[k * 64 + lane], acc);
      acc = fmaf(__shfl(xv, k), sWr[k * 64 + lane], acc);
    }
    float p0 = acc * sWc[lane * 2 + 0];
    float p1 = acc * sWc[lane * 2 + 1];
#pragma unroll
    for (int off = 32; off > 0; off >>= 1) {
      p0 += __shfl_xor(p0, off);
      p1 += __shfl_xor(p1, off);
    }
    if (lane < 2) outp[(size_t)node * 2 + lane] = ((lane == 0) ? p0 : p1) + sbc[lane];
  }
}

extern "C" void kernel_launch(void* const* d_in, const int* in_sizes, int n_in,
                              void* d_out, int out_size, void* d_ws, size_t ws_size,
                              hipStream_t stream) {
  const float* x   = (const float*)d_in[0];
  const int*   ei  = (const int*)d_in[1];
  const float* W1l = (const float*)d_in[2];
  const float* b1  = (const float*)d_in[3];
  const float* W1r = (const float*)d_in[4];
  const float* W2l = (const float*)d_in[5];
  const float* b2  = (const float*)d_in[6];
  const float* W2r = (const float*)d_in[7];
  const float* Wc  = (const float*)d_in[8];
  const float* bc  = (const float*)d_in[9];
  float* out = (float*)d_out;

  const int n  = in_sizes[0] / 64;   // 100000
  const int ne = in_sizes[1] / 2;    // 1600000
  const int* src = ei;
  const int* dst = ei + ne;

  // workspace carve
  char* ws = (char*)d_ws;
  size_t off = 0;
  auto carve = [&](size_t bytes) -> void* {
    void* p = ws + off;
    off += (bytes + 255) & ~(size_t)255;
    return p;
  };
  const int nb = (n + SCAN_BS - 1) / SCAN_BS;  // 98
  int* deg     = (int*)carve((size_t)n * 4);
  int* row_ptr = (int*)carve((size_t)(n + 1) * 4);
  int* cursor  = (int*)carve((size_t)n * 4);
  int* bsums   = (int*)carve((size_t)(nb + 1) * 4);
  int* boffs   = (int*)carve((size_t)(nb + 1) * 4);
  int* col     = (int*)carve((size_t)ne * 4);
  float* agg   = (float*)carve((size_t)n * 64 * 4);
  float* h     = (float*)carve((size_t)n * 64 * 4);
  (void)ws_size;

  // 1. degree histogram
  zero_i32_kernel<<<(n + 255) / 256, 256, 0, stream>>>(deg, n);
  hist_kernel<<<(ne + 255) / 256, 256, 0, stream>>>(dst, deg, ne);

  // 2. exclusive scan -> row_ptr, cursor
  scan_a_kernel<<<nb, SCAN_BS, 0, stream>>>(deg, row_ptr, bsums, n);
  scan_b_kernel<<<1, SCAN_BS, 0, stream>>>(bsums, boffs, nb);
  scan_c_kernel<<<(n + 256) / 256, 256, 0, stream>>>(row_ptr, cursor, boffs, n, nb);

  // 3. scatter src ids into CSR
  scatter_kernel<<<(ne + 255) / 256, 256, 0, stream>>>(src, dst, cursor, col, ne);

  // 4. layer 1: agg = mean_j x_j ; h = relu(agg@W1l + b1 + x@W1r)
  aggregate_kernel<<<(n * 64 + 255) / 256, 256, 0, stream>>>(x, row_ptr, col, agg, n);
  lin_relu_kernel<<<2048, 256, 0, stream>>>(agg, x, W1l, b1, W1r, h, n);

  // 5. layer 2 + classifier: agg2 = mean_j h_j ; out = (agg2@W2l+b2+h@W2r)@Wc+bc
  aggregate_kernel<<<(n * 64 + 255) / 256, 256, 0, stream>>>(h, row_ptr, col, agg, n);
  lin2_cls_kernel<<<2048, 256, 0, stream>>>(agg, h, W2l, b2, W2r, Wc, bc, out, n);
}

// Round 2
// 706.155 us; speedup vs baseline: 1.2305x; 1.2305x over previous
//
#include <hip/hip_runtime.h>

// ---------------------------------------------------------------------------
// GraphSAGE 2-layer (mean aggr) + linear classifier, fp32, N=100K, D=64, E=16N
// R1: break serial dependency chains.
//  - linear: 4 nodes/wave/iter -> 8 independent FMA chains; shfl(.,const k)
//    lowers to v_readlane (VALU, no LDS pipe); weights staged once per block.
//  - aggregate: edge loop unrolled x4, 4 independent accumulators -> 4 gather
//    loads in flight per wave.
// ---------------------------------------------------------------------------

#define SCAN_BS 1024

__global__ void zero_i32_kernel(int* __restrict__ p, int n) {
  int i = blockIdx.x * blockDim.x + threadIdx.x;
  if (i < n) p[i] = 0;
}

__global__ void hist_kernel(const int* __restrict__ dst, int* __restrict__ deg, int ne) {
  int e = blockIdx.x * blockDim.x + threadIdx.x;
  if (e < ne) atomicAdd(&deg[dst[e]], 1);
}

// inclusive block scan for 1024 threads (16 waves of 64)
__device__ __forceinline__ int block_scan_inclusive_1024(int v, int* wsums) {
  int lane = threadIdx.x & 63;
  int wid = threadIdx.x >> 6;
  int s = v;
#pragma unroll
  for (int off = 1; off < 64; off <<= 1) {
    int t = __shfl_up(s, off);
    if (lane >= off) s += t;
  }
  if (lane == 63) wsums[wid] = s;
  __syncthreads();
  if (wid == 0) {
    int ws = (lane < 16) ? wsums[lane] : 0;
#pragma unroll
    for (int off = 1; off < 16; off <<= 1) {
      int t = __shfl_up(ws, off);
      if (lane >= off) ws += t;
    }
    if (lane < 16) wsums[lane] = ws;
  }
  __syncthreads();
  if (wid > 0) s += wsums[wid - 1];
  return s;
}

__global__ void __launch_bounds__(SCAN_BS) scan_a_kernel(const int* __restrict__ deg,
                                                         int* __restrict__ local_excl,
                                                         int* __restrict__ bsums, int n) {
  __shared__ int wsums[16];
  int i = blockIdx.x * SCAN_BS + threadIdx.x;
  int v = (i < n) ? deg[i] : 0;
  int inc = block_scan_inclusive_1024(v, wsums);
  if (i < n) local_excl[i] = inc - v;
  if (threadIdx.x == SCAN_BS - 1) bsums[blockIdx.x] = inc;
}

__global__ void __launch_bounds__(SCAN_BS) scan_b_kernel(const int* __restrict__ bsums,
                                                         int* __restrict__ boffs, int nb) {
  __shared__ int wsums[16];
  int v = ((int)threadIdx.x < nb) ? bsums[threadIdx.x] : 0;
  int inc = block_scan_inclusive_1024(v, wsums);
  if ((int)threadIdx.x < nb) boffs[threadIdx.x] = inc - v;
  if ((int)threadIdx.x == nb - 1) boffs[nb] = inc;
}

__global__ void scan_c_kernel(int* __restrict__ row_ptr, int* __restrict__ cursor,
                              const int* __restrict__ boffs, int n, int nb) {
  int i = blockIdx.x * blockDim.x + threadIdx.x;
  if (i < n) {
    int v = row_ptr[i] + boffs[i >> 10];
    row_ptr[i] = v;
    cursor[i] = v;
  }
  if (i == n) row_ptr[n] = boffs[nb];
}

__global__ void scatter_kernel(const int* __restrict__ src, const int* __restrict__ dst,
                               int* __restrict__ cursor, int* __restrict__ col, int ne) {
  int e = blockIdx.x * blockDim.x + threadIdx.x;
  if (e < ne) {
    int d = dst[e];
    int pos = atomicAdd(&cursor[d], 1);
    col[pos] = src[e];
  }
}

// one wave per node, one feature per lane; 4 gathers in flight
__global__ void __launch_bounds__(256) aggregate_kernel(const float* __restrict__ xin,
                                                        const int* __restrict__ row_ptr,
                                                        const int* __restrict__ col,
                                                        float* __restrict__ outp, int n) {
  int gwave = (blockIdx.x * 256 + threadIdx.x) >> 6;
  int lane = threadIdx.x & 63;
  if (gwave >= n) return;
  int start = row_ptr[gwave];
  int end = row_ptr[gwave + 1];
  float acc0 = 0.0f, acc1 = 0.0f, acc2 = 0.0f, acc3 = 0.0f;
  int e = start;
  for (; e + 4 <= end; e += 4) {
    int c0 = col[e + 0];
    int c1 = col[e + 1];
    int c2 = col[e + 2];
    int c3 = col[e + 3];
    acc0 += xin[(size_t)c0 * 64 + lane];
    acc1 += xin[(size_t)c1 * 64 + lane];
    acc2 += xin[(size_t)c2 * 64 + lane];
    acc3 += xin[(size_t)c3 * 64 + lane];
  }
  for (; e < end; ++e) acc0 += xin[(size_t)col[e] * 64 + lane];
  float acc = (acc0 + acc1) + (acc2 + acc3);
  int d = end - start;
  float inv = 1.0f / (float)((d > 0) ? d : 1);
  outp[(size_t)gwave * 64 + lane] = acc * inv;
}

// out = relu(agg @ Wl + b + xin @ Wr); 4 nodes per wave per iteration
__global__ void __launch_bounds__(256) lin_relu_kernel(const float* __restrict__ agg,
                                                       const float* __restrict__ xin,
                                                       const float* __restrict__ Wl,
                                                       const float* __restrict__ bias,
                                                       const float* __restrict__ Wr,
                                                       float* __restrict__ outp, int n) {
  __shared__ float sWl[4096];
  __shared__ float sWr[4096];
  __shared__ float sb[64];
  for (int i = threadIdx.x; i < 1024; i += 256) {
    ((float4*)sWl)[i] = ((const float4*)Wl)[i];
    ((float4*)sWr)[i] = ((const float4*)Wr)[i];
  }
  if (threadIdx.x < 64) sb[threadIdx.x] = bias[threadIdx.x];
  __syncthreads();
  int lane = threadIdx.x & 63;
  int gwave = blockIdx.x * 4 + (threadIdx.x >> 6);
  int nwaves = gridDim.x * 4;
  // n is a multiple of 4, so base < n implies base+3 < n
  for (int base = gwave * 4; base < n; base += nwaves * 4) {
    const float* ap = agg + (size_t)base * 64 + lane;
    const float* xp = xin + (size_t)base * 64 + lane;
    float a0 = ap[0], a1 = ap[64], a2 = ap[128], a3 = ap[192];
    float x0 = xp[0], x1 = xp[64], x2 = xp[128], x3 = xp[192];
    float bv = sb[lane];
    float c0 = bv, c1 = bv, c2 = bv, c3 = bv;
#pragma unroll
    for (int k = 0; k < 64; ++k) {
      float wl = sWl[k * 64 + lane];
      float wr = sWr[k * 64 + lane];
      c0 = fmaf(__shfl(a0, k), wl, c0);
      c1 = fmaf(__shfl(a1, k), wl, c1);
      c2 = fmaf(__shfl(a2, k), wl, c2);
      c3 = fmaf(__shfl(a3, k), wl, c3);
      c0 = fmaf(__shfl(x0, k), wr, c0);
      c1 = fmaf(__shfl(x1, k), wr, c1);
      c2 = fmaf(__shfl(x2, k), wr, c2);
      c3 = fmaf(__shfl(x3, k), wr, c3);
    }
    float* op = outp + (size_t)base * 64 + lane;
    op[0] = fmaxf(c0, 0.0f);
    op[64] = fmaxf(c1, 0.0f);
    op[128] = fmaxf(c2, 0.0f);
    op[192] = fmaxf(c3, 0.0f);
  }
}

// h2 = agg @ Wl + b + hin @ Wr; out = h2 @ Wc + bc  -> [n, 2]
__global__ void __launch_bounds__(256) lin2_cls_kernel(const float* __restrict__ agg,
                                                       const float* __restrict__ hin,
                                                       const float* __restrict__ Wl,
                                                       const float* __restrict__ bias,
                                                       const float* __restrict__ Wr,
                                                       const float* __restrict__ Wc,
                                                       const float* __restrict__ bc,
                                                       float* __restrict__ outp, int n) {
  __shared__ float sWl[4096];
  __shared__ float sWr[4096];
  __shared__ float sb[64];
  __shared__ float sWc[128];
  __shared__ float sbc[2];
  for (int i = threadIdx.x; i < 1024; i += 256) {
    ((float4*)sWl)[i] = ((const float4*)Wl)[i];
    ((float4*)sWr)[i] = ((const float4*)Wr)[i];
  }
  if (threadIdx.x < 64) sb[threadIdx.x] = bias[threadIdx.x];
  if (threadIdx.x < 128) sWc[threadIdx.x] = Wc[threadIdx.x];
  if (threadIdx.x < 2) sbc[threadIdx.x] = bc[threadIdx.x];
  __syncthreads();
  int lane = threadIdx.x & 63;
  int gwave = blockIdx.x * 4 + (threadIdx.x >> 6);
  int nwaves = gridDim.x * 4;
  float wc0 = sWc[lane * 2 + 0];
  float wc1 = sWc[lane * 2 + 1];
  for (int base = gwave * 4; base < n; base += nwaves * 4) {
    const float* ap = agg + (size_t)base * 64 + lane;
    const float* xp = hin + (size_t)base * 64 + lane;
    float a0 = ap[0], a1 = ap[64], a2 = ap[128], a3 = ap[192];
    float x0 = xp[0], x1 = xp[64], x2 = xp[128], x3 = xp[192];
    float bv = sb[lane];
    float c0 = bv, c1 = bv, c2 = bv, c3 = bv;
#pragma unroll
    for (int k = 0; k < 64; ++k) {
      float wl = sWl[k * 64 + lane];
      float wr = sWr[k * 64 + lane];
      c0 = fmaf(__shfl(a0, k), wl, c0);
      c1 = fmaf(__shfl(a1, k), wl, c1);
      c2 = fmaf(__shfl(a2, k), wl, c2);
      c3 = fmaf(__shfl(a3, k), wl, c3);
      c0 = fmaf(__shfl(x0, k), wr, c0);
      c1 = fmaf(__shfl(x1, k), wr, c1);
      c2 = fmaf(__shfl(x2, k), wr, c2);
      c3 = fmaf(__shfl(x3, k), wr, c3);
    }
    // classifier: 8 butterfly reductions (2 outputs x 4 nodes)
    float p00 = c0 * wc0, p01 = c0 * wc1;
    float p10 = c1 * wc0, p11 = c1 * wc1;
    float p20 = c2 * wc0, p21 = c2 * wc1;
    float p30 = c3 * wc0, p31 = c3 * wc1;
#pragma unroll
    for (int off = 32; off > 0; off >>= 1) {
      p00 += __shfl_xor(p00, off); p01 += __shfl_xor(p01, off);
      p10 += __shfl_xor(p10, off); p11 += __shfl_xor(p11, off);
      p20 += __shfl_xor(p20, off); p21 += __shfl_xor(p21, off);
      p30 += __shfl_xor(p30, off); p31 += __shfl_xor(p31, off);
    }
    if (lane < 2) {
      float b2v = sbc[lane];
      outp[(size_t)(base + 0) * 2 + lane] = ((lane == 0) ? p00 : p01) + b2v;
      outp[(size_t)(base + 1) * 2 + lane] = ((lane == 0) ? p10 : p11) + b2v;
      outp[(size_t)(base + 2) * 2 + lane] = ((lane == 0) ? p20 : p21) + b2v;
      outp[(size_t)(base + 3) * 2 + lane] = ((lane == 0) ? p30 : p31) + b2v;
    }
  }
}

extern "C" void kernel_launch(void* const* d_in, const int* in_sizes, int n_in,
                              void* d_out, int out_size, void* d_ws, size_t ws_size,
                              hipStream_t stream) {
  const float* x   = (const float*)d_in[0];
  const int*   ei  = (const int*)d_in[1];
  const float* W1l = (const float*)d_in[2];
  const float* b1  = (const float*)d_in[3];
  const float* W1r = (const float*)d_in[4];
  const float* W2l = (const float*)d_in[5];
  const float* b2  = (const float*)d_in[6];
  const float* W2r = (const float*)d_in[7];
  const float* Wc  = (const float*)d_in[8];
  const float* bc  = (const float*)d_in[9];
  float* out = (float*)d_out;

  const int n  = in_sizes[0] / 64;   // 100000
  const int ne = in_sizes[1] / 2;    // 1600000
  const int* src = ei;
  const int* dst = ei + ne;

  char* ws = (char*)d_ws;
  size_t off = 0;
  auto carve = [&](size_t bytes) -> void* {
    void* p = ws + off;
    off += (bytes + 255) & ~(size_t)255;
    return p;
  };
  const int nb = (n + SCAN_BS - 1) / SCAN_BS;  // 98
  int* deg     = (int*)carve((size_t)n * 4);
  int* row_ptr = (int*)carve((size_t)(n + 1) * 4);
  int* cursor  = (int*)carve((size_t)n * 4);
  int* bsums   = (int*)carve((size_t)(nb + 1) * 4);
  int* boffs   = (int*)carve((size_t)(nb + 1) * 4);
  int* col     = (int*)carve((size_t)ne * 4);
  float* agg   = (float*)carve((size_t)n * 64 * 4);
  float* h     = (float*)carve((size_t)n * 64 * 4);
  (void)ws_size;

  zero_i32_kernel<<<(n + 255) / 256, 256, 0, stream>>>(deg, n);
  hist_kernel<<<(ne + 255) / 256, 256, 0, stream>>>(dst, deg, ne);

  scan_a_kernel<<<nb, SCAN_BS, 0, stream>>>(deg, row_ptr, bsums, n);
  scan_b_kernel<<<1, SCAN_BS, 0, stream>>>(bsums, boffs, nb);
  scan_c_kernel<<<(n + 256) / 256, 256, 0, stream>>>(row_ptr, cursor, boffs, n, nb);

  scatter_kernel<<<(ne + 255) / 256, 256, 0, stream>>>(src, dst, cursor, col, ne);

  aggregate_kernel<<<(n * 64 + 255) / 256, 256, 0, stream>>>(x, row_ptr, col, agg, n);
  lin_relu_kernel<<<2048, 256, 0, stream>>>(agg, x, W1l, b1, W1r, h, n);

  aggregate_kernel<<<(n * 64 + 255) / 256, 256, 0, stream>>>(h, row_ptr, col, agg, n);
  lin2_cls_kernel<<<2048, 256, 0, stream>>>(agg, h, W2l, b2, W2r, Wc, bc, out, n);
}

// Round 3
// 554.830 us; speedup vs baseline: 1.5661x; 1.2727x over previous
//
#include <hip/hip_runtime.h>

// ---------------------------------------------------------------------------
// GraphSAGE 2-layer (mean aggr) + linear classifier, fp32, N=100K, D=64, E=16N
// R2: kill the LDS-pipe bottleneck (shfl = ds_bpermute) in the linear layers.
//  - weights: each lane holds its output-feature column in VGPRs (128 regs).
//  - node input rows: readfirstlane-forced uniform address -> scalar loads,
//    inner loop is pure v_fma_f32 with SGPR operand. No shfl, no LDS.
//  - aggregate: scalarized col reads (saddr gathers), 8-deep unroll.
// ---------------------------------------------------------------------------

#define SCAN_BS 1024

__global__ void zero_i32_kernel(int* __restrict__ p, int n) {
  int i = blockIdx.x * blockDim.x + threadIdx.x;
  if (i < n) p[i] = 0;
}

__global__ void hist_kernel(const int* __restrict__ dst, int* __restrict__ deg, int ne) {
  int e = blockIdx.x * blockDim.x + threadIdx.x;
  if (e < ne) atomicAdd(&deg[dst[e]], 1);
}

__device__ __forceinline__ int block_scan_inclusive_1024(int v, int* wsums) {
  int lane = threadIdx.x & 63;
  int wid = threadIdx.x >> 6;
  int s = v;
#pragma unroll
  for (int off = 1; off < 64; off <<= 1) {
    int t = __shfl_up(s, off);
    if (lane >= off) s += t;
  }
  if (lane == 63) wsums[wid] = s;
  __syncthreads();
  if (wid == 0) {
    int ws = (lane < 16) ? wsums[lane] : 0;
#pragma unroll
    for (int off = 1; off < 16; off <<= 1) {
      int t = __shfl_up(ws, off);
      if (lane >= off) ws += t;
    }
    if (lane < 16) wsums[lane] = ws;
  }
  __syncthreads();
  if (wid > 0) s += wsums[wid - 1];
  return s;
}

__global__ void __launch_bounds__(SCAN_BS) scan_a_kernel(const int* __restrict__ deg,
                                                         int* __restrict__ local_excl,
                                                         int* __restrict__ bsums, int n) {
  __shared__ int wsums[16];
  int i = blockIdx.x * SCAN_BS + threadIdx.x;
  int v = (i < n) ? deg[i] : 0;
  int inc = block_scan_inclusive_1024(v, wsums);
  if (i < n) local_excl[i] = inc - v;
  if (threadIdx.x == SCAN_BS - 1) bsums[blockIdx.x] = inc;
}

__global__ void __launch_bounds__(SCAN_BS) scan_b_kernel(const int* __restrict__ bsums,
                                                         int* __restrict__ boffs, int nb) {
  __shared__ int wsums[16];
  int v = ((int)threadIdx.x < nb) ? bsums[threadIdx.x] : 0;
  int inc = block_scan_inclusive_1024(v, wsums);
  if ((int)threadIdx.x < nb) boffs[threadIdx.x] = inc - v;
  if ((int)threadIdx.x == nb - 1) boffs[nb] = inc;
}

__global__ void scan_c_kernel(int* __restrict__ row_ptr, int* __restrict__ cursor,
                              const int* __restrict__ boffs, int n, int nb) {
  int i = blockIdx.x * blockDim.x + threadIdx.x;
  if (i < n) {
    int v = row_ptr[i] + boffs[i >> 10];
    row_ptr[i] = v;
    cursor[i] = v;
  }
  if (i == n) row_ptr[n] = boffs[nb];
}

__global__ void scatter_kernel(const int* __restrict__ src, const int* __restrict__ dst,
                               int* __restrict__ cursor, int* __restrict__ col, int ne) {
  int e = blockIdx.x * blockDim.x + threadIdx.x;
  if (e < ne) {
    int d = dst[e];
    int pos = atomicAdd(&cursor[d], 1);
    col[pos] = src[e];
  }
}

// one wave per node, one feature per lane; scalarized col reads, 8 gathers in flight
__global__ void __launch_bounds__(256) aggregate_kernel(const float* __restrict__ xin,
                                                        const int* __restrict__ row_ptr,
                                                        const int* __restrict__ col,
                                                        float* __restrict__ outp, int n) {
  int gwave = (blockIdx.x * 256 + threadIdx.x) >> 6;
  int lane = threadIdx.x & 63;
  if (gwave >= n) return;
  int m = __builtin_amdgcn_readfirstlane(gwave);
  int start = row_ptr[m];
  int end = row_ptr[m + 1];
  float a0 = 0.f, a1 = 0.f, a2 = 0.f, a3 = 0.f, a4 = 0.f, a5 = 0.f, a6 = 0.f, a7 = 0.f;
  int e = start;
  for (; e + 8 <= end; e += 8) {
    int c0 = col[e + 0], c1 = col[e + 1], c2 = col[e + 2], c3 = col[e + 3];
    int c4 = col[e + 4], c5 = col[e + 5], c6 = col[e + 6], c7 = col[e + 7];
    a0 += xin[(size_t)c0 * 64 + lane];
    a1 += xin[(size_t)c1 * 64 + lane];
    a2 += xin[(size_t)c2 * 64 + lane];
    a3 += xin[(size_t)c3 * 64 + lane];
    a4 += xin[(size_t)c4 * 64 + lane];
    a5 += xin[(size_t)c5 * 64 + lane];
    a6 += xin[(size_t)c6 * 64 + lane];
    a7 += xin[(size_t)c7 * 64 + lane];
  }
  for (; e < end; ++e) a0 += xin[(size_t)col[e] * 64 + lane];
  float acc = ((a0 + a1) + (a2 + a3)) + ((a4 + a5) + (a6 + a7));
  int d = end - start;
  float inv = 1.0f / (float)((d > 0) ? d : 1);
  outp[(size_t)m * 64 + lane] = acc * inv;
}

// out = relu(agg @ Wl + b + xin @ Wr); lane = output feature, weights in VGPRs,
// input rows via uniform (scalar) loads.
__global__ void __launch_bounds__(256) lin_relu_kernel(const float* __restrict__ agg,
                                                       const float* __restrict__ xin,
                                                       const float* __restrict__ Wl,
                                                       const float* __restrict__ bias,
                                                       const float* __restrict__ Wr,
                                                       float* __restrict__ outp, int n) {
  int lane = threadIdx.x & 63;
  float wl[64], wr[64];
#pragma unroll
  for (int k = 0; k < 64; ++k) wl[k] = Wl[k * 64 + lane];
#pragma unroll
  for (int k = 0; k < 64; ++k) wr[k] = Wr[k * 64 + lane];
  float bv = bias[lane];
  int gwave = (blockIdx.x * 256 + threadIdx.x) >> 6;
  int nwaves = (gridDim.x * 256) >> 6;
  for (int node = gwave; node < n; node += nwaves) {
    int m = __builtin_amdgcn_readfirstlane(node);
    const float4* ar = (const float4*)(agg + (size_t)m * 64);
    const float4* xr = (const float4*)(xin + (size_t)m * 64);
    float accl = bv, accr = 0.0f;
#pragma unroll
    for (int k4 = 0; k4 < 16; ++k4) {
      float4 av = ar[k4];
      accl = fmaf(av.x, wl[k4 * 4 + 0], accl);
      accl = fmaf(av.y, wl[k4 * 4 + 1], accl);
      accl = fmaf(av.z, wl[k4 * 4 + 2], accl);
      accl = fmaf(av.w, wl[k4 * 4 + 3], accl);
    }
#pragma unroll
    for (int k4 = 0; k4 < 16; ++k4) {
      float4 xv = xr[k4];
      accr = fmaf(xv.x, wr[k4 * 4 + 0], accr);
      accr = fmaf(xv.y, wr[k4 * 4 + 1], accr);
      accr = fmaf(xv.z, wr[k4 * 4 + 2], accr);
      accr = fmaf(xv.w, wr[k4 * 4 + 3], accr);
    }
    outp[(size_t)m * 64 + lane] = fmaxf(accl + accr, 0.0f);
  }
}

// h2 = agg @ Wl + b + hin @ Wr; out = h2 @ Wc + bc  -> [n, 2]
__global__ void __launch_bounds__(256) lin2_cls_kernel(const float* __restrict__ agg,
                                                       const float* __restrict__ hin,
                                                       const float* __restrict__ Wl,
                                                       const float* __restrict__ bias,
                                                       const float* __restrict__ Wr,
                                                       const float* __restrict__ Wc,
                                                       const float* __restrict__ bc,
                                                       float* __restrict__ outp, int n) {
  int lane = threadIdx.x & 63;
  float wl[64], wr[64];
#pragma unroll
  for (int k = 0; k < 64; ++k) wl[k] = Wl[k * 64 + lane];
#pragma unroll
  for (int k = 0; k < 64; ++k) wr[k] = Wr[k * 64 + lane];
  float bv = bias[lane];
  float wc0 = Wc[lane * 2 + 0];
  float wc1 = Wc[lane * 2 + 1];
  float bc0 = bc[0], bc1 = bc[1];
  int gwave = (blockIdx.x * 256 + threadIdx.x) >> 6;
  int nwaves = (gridDim.x * 256) >> 6;
  for (int node = gwave; node < n; node += nwaves) {
    int m = __builtin_amdgcn_readfirstlane(node);
    const float4* ar = (const float4*)(agg + (size_t)m * 64);
    const float4* xr = (const float4*)(hin + (size_t)m * 64);
    float accl = bv, accr = 0.0f;
#pragma unroll
    for (int k4 = 0; k4 < 16; ++k4) {
      float4 av = ar[k4];
      accl = fmaf(av.x, wl[k4 * 4 + 0], accl);
      accl = fmaf(av.y, wl[k4 * 4 + 1], accl);
      accl = fmaf(av.z, wl[k4 * 4 + 2], accl);
      accl = fmaf(av.w, wl[k4 * 4 + 3], accl);
    }
#pragma unroll
    for (int k4 = 0; k4 < 16; ++k4) {
      float4 xv = xr[k4];
      accr = fmaf(xv.x, wr[k4 * 4 + 0], accr);
      accr = fmaf(xv.y, wr[k4 * 4 + 1], accr);
      accr = fmaf(xv.z, wr[k4 * 4 + 2], accr);
      accr = fmaf(xv.w, wr[k4 * 4 + 3], accr);
    }
    float c = accl + accr;
    float p0 = c * wc0, p1 = c * wc1;
#pragma unroll
    for (int off = 32; off > 0; off >>= 1) {
      p0 += __shfl_xor(p0, off);
      p1 += __shfl_xor(p1, off);
    }
    if (lane < 2) outp[(size_t)m * 2 + lane] = ((lane == 0) ? p0 : p1) + ((lane == 0) ? bc0 : bc1);
  }
}

extern "C" void kernel_launch(void* const* d_in, const int* in_sizes, int n_in,
                              void* d_out, int out_size, void* d_ws, size_t ws_size,
                              hipStream_t stream) {
  const float* x   = (const float*)d_in[0];
  const int*   ei  = (const int*)d_in[1];
  const float* W1l = (const float*)d_in[2];
  const float* b1  = (const float*)d_in[3];
  const float* W1r = (const float*)d_in[4];
  const float* W2l = (const float*)d_in[5];
  const float* b2  = (const float*)d_in[6];
  const float* W2r = (const float*)d_in[7];
  const float* Wc  = (const float*)d_in[8];
  const float* bc  = (const float*)d_in[9];
  float* out = (float*)d_out;

  const int n  = in_sizes[0] / 64;   // 100000
  const int ne = in_sizes[1] / 2;    // 1600000
  const int* src = ei;
  const int* dst = ei + ne;

  char* ws = (char*)d_ws;
  size_t off = 0;
  auto carve = [&](size_t bytes) -> void* {
    void* p = ws + off;
    off += (bytes + 255) & ~(size_t)255;
    return p;
  };
  const int nb = (n + SCAN_BS - 1) / SCAN_BS;  // 98
  int* deg     = (int*)carve((size_t)n * 4);
  int* row_ptr = (int*)carve((size_t)(n + 1) * 4);
  int* cursor  = (int*)carve((size_t)n * 4);
  int* bsums   = (int*)carve((size_t)(nb + 1) * 4);
  int* boffs   = (int*)carve((size_t)(nb + 1) * 4);
  int* col     = (int*)carve((size_t)ne * 4);
  float* agg   = (float*)carve((size_t)n * 64 * 4);
  float* h     = (float*)carve((size_t)n * 64 * 4);
  (void)ws_size;

  zero_i32_kernel<<<(n + 255) / 256, 256, 0, stream>>>(deg, n);
  hist_kernel<<<(ne + 255) / 256, 256, 0, stream>>>(dst, deg, ne);

  scan_a_kernel<<<nb, SCAN_BS, 0, stream>>>(deg, row_ptr, bsums, n);
  scan_b_kernel<<<1, SCAN_BS, 0, stream>>>(bsums, boffs, nb);
  scan_c_kernel<<<(n + 256) / 256, 256, 0, stream>>>(row_ptr, cursor, boffs, n, nb);

  scatter_kernel<<<(ne + 255) / 256, 256, 0, stream>>>(src, dst, cursor, col, ne);

  aggregate_kernel<<<(n * 64 + 255) / 256, 256, 0, stream>>>(x, row_ptr, col, agg, n);
  lin_relu_kernel<<<1024, 256, 0, stream>>>(agg, x, W1l, b1, W1r, h, n);

  aggregate_kernel<<<(n * 64 + 255) / 256, 256, 0, stream>>>(h, row_ptr, col, agg, n);
  lin2_cls_kernel<<<1024, 256, 0, stream>>>(agg, h, W2l, b2, W2r, Wc, bc, out, n);
}

// Round 4
// 542.918 us; speedup vs baseline: 1.6004x; 1.0219x over previous
//
#include <hip/hip_runtime.h>

// ---------------------------------------------------------------------------
// GraphSAGE 2-layer (mean aggr) + linear classifier, fp32, N=100K, D=64, E=16N
// R3: fix scatter write amplification (105 MB HBM writes for a 6.4 MB array).
//  dst-range-tiled scatter: 8 passes, each pass's active col region ~0.8 MB
//  stays L2-resident so lines fill up before byte-masked writeback.
//  Edge list (12.8 MB) is L3-resident across passes -> re-scan is ~free.
// ---------------------------------------------------------------------------

#define SCAN_BS 1024
#define SCATTER_PASSES 8

__global__ void zero_i32_kernel(int* __restrict__ p, int n) {
  int i = blockIdx.x * blockDim.x + threadIdx.x;
  if (i < n) p[i] = 0;
}

__global__ void hist_kernel(const int* __restrict__ dst, int* __restrict__ deg, int ne) {
  int e = blockIdx.x * blockDim.x + threadIdx.x;
  if (e < ne) atomicAdd(&deg[dst[e]], 1);
}

__device__ __forceinline__ int block_scan_inclusive_1024(int v, int* wsums) {
  int lane = threadIdx.x & 63;
  int wid = threadIdx.x >> 6;
  int s = v;
#pragma unroll
  for (int off = 1; off < 64; off <<= 1) {
    int t = __shfl_up(s, off);
    if (lane >= off) s += t;
  }
  if (lane == 63) wsums[wid] = s;
  __syncthreads();
  if (wid == 0) {
    int ws = (lane < 16) ? wsums[lane] : 0;
#pragma unroll
    for (int off = 1; off < 16; off <<= 1) {
      int t = __shfl_up(ws, off);
      if (lane >= off) ws += t;
    }
    if (lane < 16) wsums[lane] = ws;
  }
  __syncthreads();
  if (wid > 0) s += wsums[wid - 1];
  return s;
}

__global__ void __launch_bounds__(SCAN_BS) scan_a_kernel(const int* __restrict__ deg,
                                                         int* __restrict__ local_excl,
                                                         int* __restrict__ bsums, int n) {
  __shared__ int wsums[16];
  int i = blockIdx.x * SCAN_BS + threadIdx.x;
  int v = (i < n) ? deg[i] : 0;
  int inc = block_scan_inclusive_1024(v, wsums);
  if (i < n) local_excl[i] = inc - v;
  if (threadIdx.x == SCAN_BS - 1) bsums[blockIdx.x] = inc;
}

__global__ void __launch_bounds__(SCAN_BS) scan_b_kernel(const int* __restrict__ bsums,
                                                         int* __restrict__ boffs, int nb) {
  __shared__ int wsums[16];
  int v = ((int)threadIdx.x < nb) ? bsums[threadIdx.x] : 0;
  int inc = block_scan_inclusive_1024(v, wsums);
  if ((int)threadIdx.x < nb) boffs[threadIdx.x] = inc - v;
  if ((int)threadIdx.x == nb - 1) boffs[nb] = inc;
}

__global__ void scan_c_kernel(int* __restrict__ row_ptr, int* __restrict__ cursor,
                              const int* __restrict__ boffs, int n, int nb) {
  int i = blockIdx.x * blockDim.x + threadIdx.x;
  if (i < n) {
    int v = row_ptr[i] + boffs[i >> 10];
    row_ptr[i] = v;
    cursor[i] = v;
  }
  if (i == n) row_ptr[n] = boffs[nb];
}

// dst-range-tiled scatter: only edges with dst in [lo, hi) are written this pass
__global__ void scatter_pass_kernel(const int* __restrict__ src, const int* __restrict__ dst,
                                    int* __restrict__ cursor, int* __restrict__ col,
                                    int ne, int lo, int hi) {
  int e = blockIdx.x * blockDim.x + threadIdx.x;
  if (e < ne) {
    int d = dst[e];
    if (d >= lo && d < hi) {
      int pos = atomicAdd(&cursor[d], 1);
      col[pos] = src[e];
    }
  }
}

// one wave per node, one feature per lane; scalarized col reads, 8 gathers in flight
__global__ void __launch_bounds__(256) aggregate_kernel(const float* __restrict__ xin,
                                                        const int* __restrict__ row_ptr,
                                                        const int* __restrict__ col,
                                                        float* __restrict__ outp, int n) {
  int gwave = (blockIdx.x * 256 + threadIdx.x) >> 6;
  int lane = threadIdx.x & 63;
  if (gwave >= n) return;
  int m = __builtin_amdgcn_readfirstlane(gwave);
  int start = row_ptr[m];
  int end = row_ptr[m + 1];
  float a0 = 0.f, a1 = 0.f, a2 = 0.f, a3 = 0.f, a4 = 0.f, a5 = 0.f, a6 = 0.f, a7 = 0.f;
  int e = start;
  for (; e + 8 <= end; e += 8) {
    int c0 = col[e + 0], c1 = col[e + 1], c2 = col[e + 2], c3 = col[e + 3];
    int c4 = col[e + 4], c5 = col[e + 5], c6 = col[e + 6], c7 = col[e + 7];
    a0 += xin[(size_t)c0 * 64 + lane];
    a1 += xin[(size_t)c1 * 64 + lane];
    a2 += xin[(size_t)c2 * 64 + lane];
    a3 += xin[(size_t)c3 * 64 + lane];
    a4 += xin[(size_t)c4 * 64 + lane];
    a5 += xin[(size_t)c5 * 64 + lane];
    a6 += xin[(size_t)c6 * 64 + lane];
    a7 += xin[(size_t)c7 * 64 + lane];
  }
  for (; e < end; ++e) a0 += xin[(size_t)col[e] * 64 + lane];
  float acc = ((a0 + a1) + (a2 + a3)) + ((a4 + a5) + (a6 + a7));
  int d = end - start;
  float inv = 1.0f / (float)((d > 0) ? d : 1);
  outp[(size_t)m * 64 + lane] = acc * inv;
}

// out = relu(agg @ Wl + b + xin @ Wr); lane = output feature, weights in VGPRs,
// input rows via uniform (scalar) loads.
__global__ void __launch_bounds__(256) lin_relu_kernel(const float* __restrict__ agg,
                                                       const float* __restrict__ xin,
                                                       const float* __restrict__ Wl,
                                                       const float* __restrict__ bias,
                                                       const float* __restrict__ Wr,
                                                       float* __restrict__ outp, int n) {
  int lane = threadIdx.x & 63;
  float wl[64], wr[64];
#pragma unroll
  for (int k = 0; k < 64; ++k) wl[k] = Wl[k * 64 + lane];
#pragma unroll
  for (int k = 0; k < 64; ++k) wr[k] = Wr[k * 64 + lane];
  float bv = bias[lane];
  int gwave = (blockIdx.x * 256 + threadIdx.x) >> 6;
  int nwaves = (gridDim.x * 256) >> 6;
  for (int node = gwave; node < n; node += nwaves) {
    int m = __builtin_amdgcn_readfirstlane(node);
    const float4* ar = (const float4*)(agg + (size_t)m * 64);
    const float4* xr = (const float4*)(xin + (size_t)m * 64);
    float accl = bv, accr = 0.0f;
#pragma unroll
    for (int k4 = 0; k4 < 16; ++k4) {
      float4 av = ar[k4];
      accl = fmaf(av.x, wl[k4 * 4 + 0], accl);
      accl = fmaf(av.y, wl[k4 * 4 + 1], accl);
      accl = fmaf(av.z, wl[k4 * 4 + 2], accl);
      accl = fmaf(av.w, wl[k4 * 4 + 3], accl);
    }
#pragma unroll
    for (int k4 = 0; k4 < 16; ++k4) {
      float4 xv = xr[k4];
      accr = fmaf(xv.x, wr[k4 * 4 + 0], accr);
      accr = fmaf(xv.y, wr[k4 * 4 + 1], accr);
      accr = fmaf(xv.z, wr[k4 * 4 + 2], accr);
      accr = fmaf(xv.w, wr[k4 * 4 + 3], accr);
    }
    outp[(size_t)m * 64 + lane] = fmaxf(accl + accr, 0.0f);
  }
}

// h2 = agg @ Wl + b + hin @ Wr; out = h2 @ Wc + bc  -> [n, 2]
__global__ void __launch_bounds__(256) lin2_cls_kernel(const float* __restrict__ agg,
                                                       const float* __restrict__ hin,
                                                       const float* __restrict__ Wl,
                                                       const float* __restrict__ bias,
                                                       const float* __restrict__ Wr,
                                                       const float* __restrict__ Wc,
                                                       const float* __restrict__ bc,
                                                       float* __restrict__ outp, int n) {
  int lane = threadIdx.x & 63;
  float wl[64], wr[64];
#pragma unroll
  for (int k = 0; k < 64; ++k) wl[k] = Wl[k * 64 + lane];
#pragma unroll
  for (int k = 0; k < 64; ++k) wr[k] = Wr[k * 64 + lane];
  float bv = bias[lane];
  float wc0 = Wc[lane * 2 + 0];
  float wc1 = Wc[lane * 2 + 1];
  float bc0 = bc[0], bc1 = bc[1];
  int gwave = (blockIdx.x * 256 + threadIdx.x) >> 6;
  int nwaves = (gridDim.x * 256) >> 6;
  for (int node = gwave; node < n; node += nwaves) {
    int m = __builtin_amdgcn_readfirstlane(node);
    const float4* ar = (const float4*)(agg + (size_t)m * 64);
    const float4* xr = (const float4*)(hin + (size_t)m * 64);
    float accl = bv, accr = 0.0f;
#pragma unroll
    for (int k4 = 0; k4 < 16; ++k4) {
      float4 av = ar[k4];
      accl = fmaf(av.x, wl[k4 * 4 + 0], accl);
      accl = fmaf(av.y, wl[k4 * 4 + 1], accl);
      accl = fmaf(av.z, wl[k4 * 4 + 2], accl);
      accl = fmaf(av.w, wl[k4 * 4 + 3], accl);
    }
#pragma unroll
    for (int k4 = 0; k4 < 16; ++k4) {
      float4 xv = xr[k4];
      accr = fmaf(xv.x, wr[k4 * 4 + 0], accr);
      accr = fmaf(xv.y, wr[k4 * 4 + 1], accr);
      accr = fmaf(xv.z, wr[k4 * 4 + 2], accr);
      accr = fmaf(xv.w, wr[k4 * 4 + 3], accr);
    }
    float c = accl + accr;
    float p0 = c * wc0, p1 = c * wc1;
#pragma unroll
    for (int off = 32; off > 0; off >>= 1) {
      p0 += __shfl_xor(p0, off);
      p1 += __shfl_xor(p1, off);
    }
    if (lane < 2) outp[(size_t)m * 2 + lane] = ((lane == 0) ? p0 : p1) + ((lane == 0) ? bc0 : bc1);
  }
}

extern "C" void kernel_launch(void* const* d_in, const int* in_sizes, int n_in,
                              void* d_out, int out_size, void* d_ws, size_t ws_size,
                              hipStream_t stream) {
  const float* x   = (const float*)d_in[0];
  const int*   ei  = (const int*)d_in[1];
  const float* W1l = (const float*)d_in[2];
  const float* b1  = (const float*)d_in[3];
  const float* W1r = (const float*)d_in[4];
  const float* W2l = (const float*)d_in[5];
  const float* b2  = (const float*)d_in[6];
  const float* W2r = (const float*)d_in[7];
  const float* Wc  = (const float*)d_in[8];
  const float* bc  = (const float*)d_in[9];
  float* out = (float*)d_out;

  const int n  = in_sizes[0] / 64;   // 100000
  const int ne = in_sizes[1] / 2;    // 1600000
  const int* src = ei;
  const int* dst = ei + ne;

  char* ws = (char*)d_ws;
  size_t off = 0;
  auto carve = [&](size_t bytes) -> void* {
    void* p = ws + off;
    off += (bytes + 255) & ~(size_t)255;
    return p;
  };
  const int nb = (n + SCAN_BS - 1) / SCAN_BS;  // 98
  int* deg     = (int*)carve((size_t)n * 4);
  int* row_ptr = (int*)carve((size_t)(n + 1) * 4);
  int* cursor  = (int*)carve((size_t)n * 4);
  int* bsums   = (int*)carve((size_t)(nb + 1) * 4);
  int* boffs   = (int*)carve((size_t)(nb + 1) * 4);
  int* col     = (int*)carve((size_t)ne * 4);
  float* agg   = (float*)carve((size_t)n * 64 * 4);
  float* h     = (float*)carve((size_t)n * 64 * 4);
  (void)ws_size;

  zero_i32_kernel<<<(n + 255) / 256, 256, 0, stream>>>(deg, n);
  hist_kernel<<<(ne + 255) / 256, 256, 0, stream>>>(dst, deg, ne);

  scan_a_kernel<<<nb, SCAN_BS, 0, stream>>>(deg, row_ptr, bsums, n);
  scan_b_kernel<<<1, SCAN_BS, 0, stream>>>(bsums, boffs, nb);
  scan_c_kernel<<<(n + 256) / 256, 256, 0, stream>>>(row_ptr, cursor, boffs, n, nb);

  // dst-range-tiled scatter: active col region per pass ~0.8 MB (L2-resident)
  {
    int W = (n + SCATTER_PASSES - 1) / SCATTER_PASSES;
    for (int p = 0; p < SCATTER_PASSES; ++p) {
      int lo = p * W;
      int hi = (lo + W < n) ? (lo + W) : n;
      scatter_pass_kernel<<<(ne + 255) / 256, 256, 0, stream>>>(src, dst, cursor, col, ne, lo, hi);
    }
  }

  aggregate_kernel<<<(n * 64 + 255) / 256, 256, 0, stream>>>(x, row_ptr, col, agg, n);
  lin_relu_kernel<<<1024, 256, 0, stream>>>(agg, x, W1l, b1, W1r, h, n);

  aggregate_kernel<<<(n * 64 + 255) / 256, 256, 0, stream>>>(h, row_ptr, col, agg, n);
  lin2_cls_kernel<<<1024, 256, 0, stream>>>(agg, h, W2l, b2, W2r, Wc, bc, out, n);
}

// Round 5
// 521.884 us; speedup vs baseline: 1.6649x; 1.0403x over previous
//
#include <hip/hip_runtime.h>

// ---------------------------------------------------------------------------
// GraphSAGE 2-layer (mean aggr) + linear classifier, fp32, N=100K, D=64, E=16N
// R4: linear layers as thread-per-node with WAVE-UNIFORM weight addresses.
//  W[k][j] indexed by unrolled constants only -> s_load (SGPR operand), inner
//  loop is pure v_fmac_f32 with 32 independent chains. Two uniform j-half
//  passes bound the live scalar set. No shfl, no LDS, no per-lane weight regs.
// ---------------------------------------------------------------------------

#define SCAN_BS 1024
#define SCATTER_PASSES 8

__global__ void zero_i32_kernel(int* __restrict__ p, int n) {
  int i = blockIdx.x * blockDim.x + threadIdx.x;
  if (i < n) p[i] = 0;
}

__global__ void hist_kernel(const int* __restrict__ dst, int* __restrict__ deg, int ne) {
  int e = blockIdx.x * blockDim.x + threadIdx.x;
  if (e < ne) atomicAdd(&deg[dst[e]], 1);
}

__device__ __forceinline__ int block_scan_inclusive_1024(int v, int* wsums) {
  int lane = threadIdx.x & 63;
  int wid = threadIdx.x >> 6;
  int s = v;
#pragma unroll
  for (int off = 1; off < 64; off <<= 1) {
    int t = __shfl_up(s, off);
    if (lane >= off) s += t;
  }
  if (lane == 63) wsums[wid] = s;
  __syncthreads();
  if (wid == 0) {
    int ws = (lane < 16) ? wsums[lane] : 0;
#pragma unroll
    for (int off = 1; off < 16; off <<= 1) {
      int t = __shfl_up(ws, off);
      if (lane >= off) ws += t;
    }
    if (lane < 16) wsums[lane] = ws;
  }
  __syncthreads();
  if (wid > 0) s += wsums[wid - 1];
  return s;
}

__global__ void __launch_bounds__(SCAN_BS) scan_a_kernel(const int* __restrict__ deg,
                                                         int* __restrict__ local_excl,
                                                         int* __restrict__ bsums, int n) {
  __shared__ int wsums[16];
  int i = blockIdx.x * SCAN_BS + threadIdx.x;
  int v = (i < n) ? deg[i] : 0;
  int inc = block_scan_inclusive_1024(v, wsums);
  if (i < n) local_excl[i] = inc - v;
  if (threadIdx.x == SCAN_BS - 1) bsums[blockIdx.x] = inc;
}

__global__ void __launch_bounds__(SCAN_BS) scan_b_kernel(const int* __restrict__ bsums,
                                                         int* __restrict__ boffs, int nb) {
  __shared__ int wsums[16];
  int v = ((int)threadIdx.x < nb) ? bsums[threadIdx.x] : 0;
  int inc = block_scan_inclusive_1024(v, wsums);
  if ((int)threadIdx.x < nb) boffs[threadIdx.x] = inc - v;
  if ((int)threadIdx.x == nb - 1) boffs[nb] = inc;
}

__global__ void scan_c_kernel(int* __restrict__ row_ptr, int* __restrict__ cursor,
                              const int* __restrict__ boffs, int n, int nb) {
  int i = blockIdx.x * blockDim.x + threadIdx.x;
  if (i < n) {
    int v = row_ptr[i] + boffs[i >> 10];
    row_ptr[i] = v;
    cursor[i] = v;
  }
  if (i == n) row_ptr[n] = boffs[nb];
}

__global__ void scatter_pass_kernel(const int* __restrict__ src, const int* __restrict__ dst,
                                    int* __restrict__ cursor, int* __restrict__ col,
                                    int ne, int lo, int hi) {
  int e = blockIdx.x * blockDim.x + threadIdx.x;
  if (e < ne) {
    int d = dst[e];
    if (d >= lo && d < hi) {
      int pos = atomicAdd(&cursor[d], 1);
      col[pos] = src[e];
    }
  }
}

// one wave per node, one feature per lane; scalarized col reads, 8 gathers in flight
__global__ void __launch_bounds__(256) aggregate_kernel(const float* __restrict__ xin,
                                                        const int* __restrict__ row_ptr,
                                                        const int* __restrict__ col,
                                                        float* __restrict__ outp, int n) {
  int gwave = (blockIdx.x * 256 + threadIdx.x) >> 6;
  int lane = threadIdx.x & 63;
  if (gwave >= n) return;
  int m = __builtin_amdgcn_readfirstlane(gwave);
  int start = row_ptr[m];
  int end = row_ptr[m + 1];
  float a0 = 0.f, a1 = 0.f, a2 = 0.f, a3 = 0.f, a4 = 0.f, a5 = 0.f, a6 = 0.f, a7 = 0.f;
  int e = start;
  for (; e + 8 <= end; e += 8) {
    int c0 = col[e + 0], c1 = col[e + 1], c2 = col[e + 2], c3 = col[e + 3];
    int c4 = col[e + 4], c5 = col[e + 5], c6 = col[e + 6], c7 = col[e + 7];
    a0 += xin[(size_t)c0 * 64 + lane];
    a1 += xin[(size_t)c1 * 64 + lane];
    a2 += xin[(size_t)c2 * 64 + lane];
    a3 += xin[(size_t)c3 * 64 + lane];
    a4 += xin[(size_t)c4 * 64 + lane];
    a5 += xin[(size_t)c5 * 64 + lane];
    a6 += xin[(size_t)c6 * 64 + lane];
    a7 += xin[(size_t)c7 * 64 + lane];
  }
  for (; e < end; ++e) a0 += xin[(size_t)col[e] * 64 + lane];
  float acc = ((a0 + a1) + (a2 + a3)) + ((a4 + a5) + (a6 + a7));
  int d = end - start;
  float inv = 1.0f / (float)((d > 0) ? d : 1);
  outp[(size_t)m * 64 + lane] = acc * inv;
}

// out = relu(agg @ Wl + b + xin @ Wr); thread-per-node, uniform weight s_loads,
// two j-half passes (acc[32] each) to bound live SGPRs.
__global__ void __launch_bounds__(256) lin_relu_kernel(const float* __restrict__ agg,
                                                       const float* __restrict__ xin,
                                                       const float* __restrict__ Wl,
                                                       const float* __restrict__ bias,
                                                       const float* __restrict__ Wr,
                                                       float* __restrict__ outp, int n) {
  int node = blockIdx.x * 256 + threadIdx.x;
  if (node >= n) return;
  const float4* ar = (const float4*)(agg + (size_t)node * 64);
  const float4* xr = (const float4*)(xin + (size_t)node * 64);
#pragma unroll
  for (int h = 0; h < 2; ++h) {  // uniform half index
    const float* wl = Wl + h * 32;
    const float* wr = Wr + h * 32;
    float acc[32];
#pragma unroll
    for (int j = 0; j < 32; ++j) acc[j] = bias[h * 32 + j];  // uniform -> s_load
#pragma unroll
    for (int k4 = 0; k4 < 16; ++k4) {
      float4 av = ar[k4];
      float4 xv = xr[k4];
#pragma unroll
      for (int j = 0; j < 32; ++j) {
        acc[j] = fmaf(av.x, wl[(k4 * 4 + 0) * 64 + j], acc[j]);
        acc[j] = fmaf(av.y, wl[(k4 * 4 + 1) * 64 + j], acc[j]);
        acc[j] = fmaf(av.z, wl[(k4 * 4 + 2) * 64 + j], acc[j]);
        acc[j] = fmaf(av.w, wl[(k4 * 4 + 3) * 64 + j], acc[j]);
        acc[j] = fmaf(xv.x, wr[(k4 * 4 + 0) * 64 + j], acc[j]);
        acc[j] = fmaf(xv.y, wr[(k4 * 4 + 1) * 64 + j], acc[j]);
        acc[j] = fmaf(xv.z, wr[(k4 * 4 + 2) * 64 + j], acc[j]);
        acc[j] = fmaf(xv.w, wr[(k4 * 4 + 3) * 64 + j], acc[j]);
      }
    }
    float4* op = (float4*)(outp + (size_t)node * 64 + h * 32);
#pragma unroll
    for (int j4 = 0; j4 < 8; ++j4) {
      float4 v;
      v.x = fmaxf(acc[j4 * 4 + 0], 0.f);
      v.y = fmaxf(acc[j4 * 4 + 1], 0.f);
      v.z = fmaxf(acc[j4 * 4 + 2], 0.f);
      v.w = fmaxf(acc[j4 * 4 + 3], 0.f);
      op[j4] = v;
    }
  }
}

// h2 = agg @ Wl + b + hin @ Wr; out = h2 @ Wc + bc  -> [n, 2]
// thread-per-node; classifier folded into each half-pass epilogue (uniform Wc).
__global__ void __launch_bounds__(256) lin2_cls_kernel(const float* __restrict__ agg,
                                                       const float* __restrict__ hin,
                                                       const float* __restrict__ Wl,
                                                       const float* __restrict__ bias,
                                                       const float* __restrict__ Wr,
                                                       const float* __restrict__ Wc,
                                                       const float* __restrict__ bc,
                                                       float* __restrict__ outp, int n) {
  int node = blockIdx.x * 256 + threadIdx.x;
  if (node >= n) return;
  const float4* ar = (const float4*)(agg + (size_t)node * 64);
  const float4* xr = (const float4*)(hin + (size_t)node * 64);
  float p0 = bc[0], p1 = bc[1];  // uniform s_loads
#pragma unroll
  for (int h = 0; h < 2; ++h) {
    const float* wl = Wl + h * 32;
    const float* wr = Wr + h * 32;
    float acc[32];
#pragma unroll
    for (int j = 0; j < 32; ++j) acc[j] = bias[h * 32 + j];
#pragma unroll
    for (int k4 = 0; k4 < 16; ++k4) {
      float4 av = ar[k4];
      float4 xv = xr[k4];
#pragma unroll
      for (int j = 0; j < 32; ++j) {
        acc[j] = fmaf(av.x, wl[(k4 * 4 + 0) * 64 + j], acc[j]);
        acc[j] = fmaf(av.y, wl[(k4 * 4 + 1) * 64 + j], acc[j]);
        acc[j] = fmaf(av.z, wl[(k4 * 4 + 2) * 64 + j], acc[j]);
        acc[j] = fmaf(av.w, wl[(k4 * 4 + 3) * 64 + j], acc[j]);
        acc[j] = fmaf(xv.x, wr[(k4 * 4 + 0) * 64 + j], acc[j]);
        acc[j] = fmaf(xv.y, wr[(k4 * 4 + 1) * 64 + j], acc[j]);
        acc[j] = fmaf(xv.z, wr[(k4 * 4 + 2) * 64 + j], acc[j]);
        acc[j] = fmaf(xv.w, wr[(k4 * 4 + 3) * 64 + j], acc[j]);
      }
    }
#pragma unroll
    for (int j = 0; j < 32; ++j) {
      p0 = fmaf(acc[j], Wc[(h * 32 + j) * 2 + 0], p0);  // uniform -> s_load
      p1 = fmaf(acc[j], Wc[(h * 32 + j) * 2 + 1], p1);
    }
  }
  float2 o;
  o.x = p0;
  o.y = p1;
  *(float2*)(outp + (size_t)node * 2) = o;
}

extern "C" void kernel_launch(void* const* d_in, const int* in_sizes, int n_in,
                              void* d_out, int out_size, void* d_ws, size_t ws_size,
                              hipStream_t stream) {
  const float* x   = (const float*)d_in[0];
  const int*   ei  = (const int*)d_in[1];
  const float* W1l = (const float*)d_in[2];
  const float* b1  = (const float*)d_in[3];
  const float* W1r = (const float*)d_in[4];
  const float* W2l = (const float*)d_in[5];
  const float* b2  = (const float*)d_in[6];
  const float* W2r = (const float*)d_in[7];
  const float* Wc  = (const float*)d_in[8];
  const float* bc  = (const float*)d_in[9];
  float* out = (float*)d_out;

  const int n  = in_sizes[0] / 64;   // 100000
  const int ne = in_sizes[1] / 2;    // 1600000
  const int* src = ei;
  const int* dst = ei + ne;

  char* ws = (char*)d_ws;
  size_t off = 0;
  auto carve = [&](size_t bytes) -> void* {
    void* p = ws + off;
    off += (bytes + 255) & ~(size_t)255;
    return p;
  };
  const int nb = (n + SCAN_BS - 1) / SCAN_BS;  // 98
  int* deg     = (int*)carve((size_t)n * 4);
  int* row_ptr = (int*)carve((size_t)(n + 1) * 4);
  int* cursor  = (int*)carve((size_t)n * 4);
  int* bsums   = (int*)carve((size_t)(nb + 1) * 4);
  int* boffs   = (int*)carve((size_t)(nb + 1) * 4);
  int* col     = (int*)carve((size_t)ne * 4);
  float* agg   = (float*)carve((size_t)n * 64 * 4);
  float* h     = (float*)carve((size_t)n * 64 * 4);
  (void)ws_size;

  zero_i32_kernel<<<(n + 255) / 256, 256, 0, stream>>>(deg, n);
  hist_kernel<<<(ne + 255) / 256, 256, 0, stream>>>(dst, deg, ne);

  scan_a_kernel<<<nb, SCAN_BS, 0, stream>>>(deg, row_ptr, bsums, n);
  scan_b_kernel<<<1, SCAN_BS, 0, stream>>>(bsums, boffs, nb);
  scan_c_kernel<<<(n + 256) / 256, 256, 0, stream>>>(row_ptr, cursor, boffs, n, nb);

  {
    int W = (n + SCATTER_PASSES - 1) / SCATTER_PASSES;
    for (int p = 0; p < SCATTER_PASSES; ++p) {
      int lo = p * W;
      int hi = (lo + W < n) ? (lo + W) : n;
      scatter_pass_kernel<<<(ne + 255) / 256, 256, 0, stream>>>(src, dst, cursor, col, ne, lo, hi);
    }
  }

  aggregate_kernel<<<(n * 64 + 255) / 256, 256, 0, stream>>>(x, row_ptr, col, agg, n);
  lin_relu_kernel<<<(n + 255) / 256, 256, 0, stream>>>(agg, x, W1l, b1, W1r, h, n);

  aggregate_kernel<<<(n * 64 + 255) / 256, 256, 0, stream>>>(h, row_ptr, col, agg, n);
  lin2_cls_kernel<<<(n + 255) / 256, 256, 0, stream>>>(agg, h, W2l, b2, W2r, Wc, bc, out, n);
}